// Round 9
// baseline (206.494 us; speedup 1.0000x reference)
//
#include <hip/hip_runtime.h>
#include <hip/hip_bf16.h>

#define BB 8
#define NN 2048
#define VV 256
#define HH 1024
#define CHK 64
#define RPC 32
constexpr float EPS = 1e-5f;

typedef __attribute__((ext_vector_type(4))) float floatx4;
typedef __attribute__((ext_vector_type(8))) short short8;

__device__ __forceinline__ void load_lds16(const void* g, void* l) {
    __builtin_amdgcn_global_load_lds((const __attribute__((address_space(1))) void*)g,
                                     (__attribute__((address_space(3))) void*)l, 16, 0, 0);
}
__device__ __forceinline__ float bf16s_to_f(short s) {
    unsigned u = ((unsigned)(unsigned short)s) << 16;
    return __builtin_bit_cast(float, u);
}

// ---------------------------------------------------------------------------
// K1: merged prep (blocks 0..8) + weight bf16 convert (blocks 9..)
// ---------------------------------------------------------------------------
__global__ void prep_cvt_kernel(const float* __restrict__ h,
                                const float* __restrict__ g_attn, const float* __restrict__ b_attn,
                                const float* __restrict__ g_mlp,  const float* __restrict__ b_mlp,
                                const float* __restrict__ qk_dir,
                                const float* __restrict__ wo_w,  const float* __restrict__ wv_bos,
                                const float* __restrict__ w1, const float* __restrict__ w2,
                                float* __restrict__ attn_row0, float* __restrict__ mlp_row0,
                                float* __restrict__ v_bos, float* __restrict__ sum0,
                                __hip_bfloat16* __restrict__ w1b, __hip_bfloat16* __restrict__ w2b)
{
    int t = threadIdx.x;
    if (blockIdx.x > BB) {
        int i = ((blockIdx.x - BB - 1) * 256 + t) * 4;
        const float* src;
        __hip_bfloat16* dst;
        if (i < HH * VV) { src = w1 + i; dst = w1b + i; }
        else             { src = w2 + (i - HH * VV); dst = w2b + (i - HH * VV); }
        float4 x = *reinterpret_cast<const float4*>(src);
        dst[0] = __float2bfloat16(x.x);
        dst[1] = __float2bfloat16(x.y);
        dst[2] = __float2bfloat16(x.z);
        dst[3] = __float2bfloat16(x.w);
        return;
    }
    __shared__ float red[VV];
    if (blockIdx.x < BB) {
        int b = blockIdx.x;
        float x = h[(size_t)b * NN * VV + t];
        red[t] = x; __syncthreads();
        for (int s = 128; s > 0; s >>= 1) { if (t < s) red[t] += red[t + s]; __syncthreads(); }
        float m = red[0] * (1.0f / VV); __syncthreads();
        float xc = x - m;
        red[t] = xc * xc; __syncthreads();
        for (int s = 128; s > 0; s >>= 1) { if (t < s) red[t] += red[t + s]; __syncthreads(); }
        float var = red[0] * (1.0f / VV); __syncthreads();
        float inv = 1.0f / sqrtf(var + EPS);
        float an = xc * inv * g_attn[t] + b_attn[t];
        float mn = xc * inv * g_mlp[t] + b_mlp[t];
        attn_row0[b * VV + t] = an;
        mlp_row0[b * VV + t]  = mn;
        red[t] = an * qk_dir[t]; __syncthreads();
        for (int s = 128; s > 0; s >>= 1) { if (t < s) red[t] += red[t + s]; __syncthreads(); }
        if (t == 0) sum0[b] = red[0];
    } else {
        const float4* wp = reinterpret_cast<const float4*>(wo_w + (size_t)t * VV);
        const float4* vp = reinterpret_cast<const float4*>(wv_bos);
        float acc = 0.f;
        for (int j = 0; j < VV / 4; ++j) {
            float4 a = wp[j], b = vp[j];
            acc += a.x * b.x + a.y * b.y + a.z * b.z + a.w * b.w;
        }
        v_bos[t] = acc;
    }
}

// ---------------------------------------------------------------------------
// K2: fused pass over h: bf16 convert (BOS row swap), softmax weights, and
//     scan chunk partials (bf16-rounded for consistency with attn_kernel).
// ---------------------------------------------------------------------------
__global__ __launch_bounds__(256) void scan_qkw_cvt_kernel(
    const float* __restrict__ h, const float* __restrict__ mlp_row0,
    const float* __restrict__ wv,
    const float* __restrict__ qk_bos, const float* __restrict__ qk_prev,
    const float* __restrict__ sum0,
    short* __restrict__ Xb,
    float* __restrict__ w0, float* __restrict__ wprev, float* __restrict__ wz,
    float* __restrict__ chunkSum)
{
    __shared__ float lds[4][VV];
    int wave = threadIdx.x >> 6, lane = threadIdx.x & 63;
    int b = blockIdx.x / CHK, c = blockIdx.x % CHK;
    int r0 = c * RPC + wave * 8;
    float4 wv4 = reinterpret_cast<const float4*>(wv)[lane];
    float4 qb4 = reinterpret_cast<const float4*>(qk_bos)[lane];
    float4 qp4 = reinterpret_cast<const float4*>(qk_prev)[lane];
    float s0b = sum0[b];
    float4 vsum = {0.f, 0.f, 0.f, 0.f};
#pragma unroll
    for (int rr = 0; rr < 8; ++rr) {
        int r = r0 + rr;
        size_t base = ((size_t)b * NN + r) * VV;
        float4 x = *reinterpret_cast<const float4*>(h + base + lane * 4);
        float4 xs = x;
        if (r == 0) xs = *reinterpret_cast<const float4*>(mlp_row0 + b * VV + lane * 4);
        __hip_bfloat16 c0 = __float2bfloat16(xs.x), c1 = __float2bfloat16(xs.y),
                       c2 = __float2bfloat16(xs.z), c3 = __float2bfloat16(xs.w);
        short4 pk;
        pk.x = *reinterpret_cast<short*>(&c0);
        pk.y = *reinterpret_cast<short*>(&c1);
        pk.z = *reinterpret_cast<short*>(&c2);
        pk.w = *reinterpret_cast<short*>(&c3);
        *reinterpret_cast<short4*>(Xb + base + lane * 4) = pk;
        if (r != 0) {
            vsum.x += bf16s_to_f(pk.x) * wv4.x; vsum.y += bf16s_to_f(pk.y) * wv4.y;
            vsum.z += bf16s_to_f(pk.z) * wv4.z; vsum.w += bf16s_to_f(pk.w) * wv4.w;
        }
        float s1 = x.x * qb4.x + x.y * qb4.y + x.z * qb4.z + x.w * qb4.w;
        float s2 = x.x * qp4.x + x.y * qp4.y + x.z * qp4.z + x.w * qp4.w;
        for (int off = 32; off > 0; off >>= 1) {
            s1 += __shfl_down(s1, off);
            s2 += __shfl_down(s2, off);
        }
        if (lane == 0) {
            int gid = b * NN + r;
            float W0, WP, WZ;
            if (r == 0) { W0 = 1.f; WP = 0.f; WZ = 0.f; }
            else if (r == 1) {
                float a = s1 * s0b + s2;
                float m = fmaxf(a, 0.f);
                float ea = expf(a - m), ez = expf(-m);
                float Z = ea + ez;
                W0 = ea / Z; WZ = ez / Z; WP = WZ;
            } else {
                float a = s1 * s0b;
                float m = fmaxf(fmaxf(a, s2), 0.f);
                float ea = expf(a - m), ed = expf(s2 - m), ez = expf(-m);
                float Z = ea + ed + (float)(r - 1) * ez;
                W0 = ea / Z; WP = ed / Z; WZ = ez / Z;
            }
            w0[gid] = W0; wprev[gid] = WP; wz[gid] = WZ;
        }
    }
    reinterpret_cast<float4*>(lds[wave])[lane] = vsum;
    __syncthreads();
    int v = threadIdx.x;
    chunkSum[((size_t)b * CHK + c) * VV + v] = lds[0][v] + lds[1][v] + lds[2][v] + lds[3][v];
}

// ---------------------------------------------------------------------------
// K3: attention emit (standalone, writes out first) — inline chunk prefix.
// ---------------------------------------------------------------------------
__global__ __launch_bounds__(128) void attn_kernel(
    const short* __restrict__ Xb, const float* __restrict__ wv,
    const float* __restrict__ v_bos,
    const float* __restrict__ w0, const float* __restrict__ wprev,
    const float* __restrict__ wz, const float* __restrict__ chunkSum,
    float* __restrict__ out)
{
    int b = blockIdx.x / CHK, c = blockIdx.x % CHK;
    int v = threadIdx.x * 2;
    float2 wv2 = *reinterpret_cast<const float2*>(wv + v);
    float2 vb2 = *reinterpret_cast<const float2*>(v_bos + v);
    float2 S = {0.f, 0.f};
    for (int cc = 0; cc < c; ++cc) {
        float2 t = *reinterpret_cast<const float2*>(chunkSum + (b * CHK + cc) * VV + v);
        S.x += t.x; S.y += t.y;
    }
    int r0 = c * RPC;
    float2 prev = {0.f, 0.f};
    if (r0 > 0) {
        short2 p = *reinterpret_cast<const short2*>(Xb + ((size_t)b * NN + r0 - 1) * VV + v);
        prev.x = bf16s_to_f(p.x) * wv2.x; prev.y = bf16s_to_f(p.y) * wv2.y;
    }
    for (int r = r0; r < r0 + RPC; ++r) {
        size_t idx = ((size_t)b * NN + r) * VV + v;
        float2 o;
        if (r == 0) {
            o = vb2;
            prev.x = 0.f; prev.y = 0.f;
        } else {
            short2 xv = *reinterpret_cast<const short2*>(Xb + idx);
            float2 val;
            val.x = bf16s_to_f(xv.x) * wv2.x; val.y = bf16s_to_f(xv.y) * wv2.y;
            S.x += val.x; S.y += val.y;
            int wi = b * NN + r;
            float W0 = w0[wi], WD = wprev[wi] - wz[wi], WZ = wz[wi];
            o.x = W0 * vb2.x + WD * prev.x + WZ * S.x;
            o.y = W0 * vb2.y + WD * prev.y + WZ * S.y;
            prev = val;
        }
        *reinterpret_cast<float2*>(out + idx) = o;
    }
}

// ---------------------------------------------------------------------------
// K4: MLP via Y^T trick.  out += relu(X @ w1^T) @ w2^T
//   grid 256 (1/CU), 1024 thr = 16 waves (wm 4 x wh 4), M-tile 64.
//   GEMM1 computes Y^T[h-slice 16][m-slice 16] (A=w1 LDS, B=X regs): C-layout
//   col = m = lane&15, row = h = q*4+reg — which IS the A-fragment layout for
//   a K=16 contraction. GEMM2 runs as zero-padded 16x16x32 MFMA (high 4 k of
//   both A and B = 0) entirely from registers over the wave's h-slice.
//   => no sY, no mid barrier: ONE barrier per hc, dbuf weights (128 KB LDS).
//   Per-wave partial oacc[m16][v256] (64 VGPR) reduced over wh via LDS at end,
//   then cooperative out += (attn wrote out first).
// ---------------------------------------------------------------------------
__global__ __launch_bounds__(1024) void mlp_tp(const short* __restrict__ Xb,
                                               const short* __restrict__ w1b,
                                               const short* __restrict__ w2b,
                                               float* __restrict__ out)
{
    __shared__ __align__(16) short smem[65536];   // 128 KB
    // sW1[buf] = smem + buf*16384            [64 h][256 k], seg-swizzled
    // sW2[buf] = smem + 32768 + buf*16384    [256 v][64 h], seg-swizzled
    // epilogue: red = (float*)smem, [4 wm][16 m][260 v] (66.5 KB)
    int wave = threadIdx.x >> 6, lane = threadIdx.x & 63;
    int wm = wave & 3, wh = wave >> 2;
    int ra = lane & 15, q = lane >> 4;
    int m0 = blockIdx.x * 64;

    // X fragments: this wave's m-slice (16 rows), full K=256 (32 VGPR)
    short8 xf[8];
#pragma unroll
    for (int ks = 0; ks < 8; ++ks)
        xf[ks] = *reinterpret_cast<const short8*>(
            Xb + (size_t)(m0 + wm * 16 + ra) * VV + ks * 32 + q * 8);

    floatx4 oacc[16];
#pragma unroll
    for (int j = 0; j < 16; ++j) oacc[j] = floatx4{0.f, 0.f, 0.f, 0.f};

    auto stage = [&](int hc, int buf) {
        // sW1: 64 rows x 512 B; 32 DMA instr (2 rows each), 2 per wave
#pragma unroll
        for (int it = 0; it < 2; ++it) {
            int g = wave * 2 + it;
            int n = g * 2 + (lane >> 5);
            int slot = lane & 31;
            load_lds16(w1b + (size_t)(hc * 64 + n) * VV + ((slot ^ (n & 7)) * 8),
                       smem + buf * 16384 + g * 512);
        }
        // sW2: 256 rows x 128 B; 32 DMA instr (8 rows each), 2 per wave
#pragma unroll
        for (int it = 0; it < 2; ++it) {
            int g = wave * 2 + it;
            int v = g * 8 + (lane >> 3);
            int slot = lane & 7;
            load_lds16(w2b + (size_t)v * HH + hc * 64 + ((slot ^ (v & 7)) * 8),
                       smem + 32768 + buf * 16384 + g * 512);
        }
    };

    int hrow = wh * 16 + ra;
    stage(0, 0);
    for (int hc = 0; hc < 16; ++hc) {
        int p = hc & 1;
        __syncthreads();                 // buf[p] staged+visible
        if (hc < 15) stage(hc + 1, p ^ 1);   // DMA runs under full G1+G2 body

        // ---- GEMM1: Y^T[h-slice 16][m-slice 16] = w1c @ X^T ----
        floatx4 yacc = floatx4{0.f, 0.f, 0.f, 0.f};
        const short* sW1p = smem + p * 16384;
#pragma unroll
        for (int ks = 0; ks < 8; ++ks) {
            short8 af = *reinterpret_cast<const short8*>(
                sW1p + hrow * 256 + (((ks * 4 + q) ^ (ra & 7)) * 8));
            yacc = __builtin_amdgcn_mfma_f32_16x16x32_bf16(af, xf[ks], yacc, 0, 0, 0);
        }
        // relu + bf16: yacc C-layout == A-frag (K=16) layout; zero-pad high 4 k
        __hip_bfloat16 y0 = __float2bfloat16(fmaxf(yacc[0], 0.f));
        __hip_bfloat16 y1 = __float2bfloat16(fmaxf(yacc[1], 0.f));
        __hip_bfloat16 y2 = __float2bfloat16(fmaxf(yacc[2], 0.f));
        __hip_bfloat16 y3 = __float2bfloat16(fmaxf(yacc[3], 0.f));
        short8 a2 = {*reinterpret_cast<short*>(&y0), *reinterpret_cast<short*>(&y1),
                     *reinterpret_cast<short*>(&y2), *reinterpret_cast<short*>(&y3),
                     (short)0, (short)0, (short)0, (short)0};

        // ---- GEMM2: oacc[m16][v256] += Y^T-slice @ w2c^T (zero-padded K) ----
        const short* sW2p = smem + 32768 + p * 16384;
        int pseg = (wh * 2 + (q >> 1));
        int hoff = (q & 1) * 4;
#pragma unroll
        for (int j = 0; j < 16; ++j) {
            int v = j * 16 + ra;
            short4 bl = *reinterpret_cast<const short4*>(
                sW2p + v * 64 + ((pseg ^ (ra & 7)) * 8) + hoff);
            short8 b2 = {bl.x, bl.y, bl.z, bl.w, (short)0, (short)0, (short)0, (short)0};
            oacc[j] = __builtin_amdgcn_mfma_f32_16x16x32_bf16(a2, b2, oacc[j], 0, 0, 0);
        }
    }

    // ---- reduce oacc over wh via LDS; pitch 260 floats (2-way banks, 16B ok) ----
    float* red = reinterpret_cast<float*>(smem);
    int rbase = wm * 4160;   // 16*260
#pragma unroll 1
    for (int ph = 1; ph < 4; ++ph) {
        __syncthreads();
        if (wh == ph) {
#pragma unroll
            for (int j = 0; j < 16; ++j)
#pragma unroll
                for (int r = 0; r < 4; ++r)
                    red[rbase + (q * 4 + r) * 260 + j * 16 + ra] = oacc[j][r];
        }
        __syncthreads();
        if (wh == 0) {
#pragma unroll
            for (int j = 0; j < 16; ++j)
#pragma unroll
                for (int r = 0; r < 4; ++r)
                    oacc[j][r] += red[rbase + (q * 4 + r) * 260 + j * 16 + ra];
        }
    }
    __syncthreads();
    if (wh == 0) {
#pragma unroll
        for (int j = 0; j < 16; ++j)
#pragma unroll
            for (int r = 0; r < 4; ++r)
                red[rbase + (q * 4 + r) * 260 + j * 16 + ra] = oacc[j][r];
    }
    __syncthreads();

    // ---- cooperative epilogue: out += red  (attn already wrote out) ----
    int t = threadIdx.x;
#pragma unroll
    for (int rep = 0; rep < 4; ++rep) {
        int idx = rep * 4096 + t * 4;          // element in [64][256]
        int m = idx >> 8, v = idx & 255;
        float4 s = *reinterpret_cast<const float4*>(&red[(m >> 4) * 4160 + (m & 15) * 260 + v]);
        float* op = out + (size_t)(m0 + m) * VV + v;
        float4 o = *reinterpret_cast<const float4*>(op);
        o.x += s.x; o.y += s.y; o.z += s.z; o.w += s.w;
        *reinterpret_cast<float4*>(op) = o;
    }
}

// ---------------------------------------------------------------------------
extern "C" void kernel_launch(void* const* d_in, const int* in_sizes, int n_in,
                              void* d_out, int out_size, void* d_ws, size_t ws_size,
                              hipStream_t stream)
{
    const float* h        = (const float*)d_in[0];
    const float* ln_attn_g = (const float*)d_in[3];
    const float* ln_attn_b = (const float*)d_in[4];
    const float* ln_mlp_g  = (const float*)d_in[5];
    const float* ln_mlp_b  = (const float*)d_in[6];
    const float* wv        = (const float*)d_in[7];
    const float* wv_bos    = (const float*)d_in[8];
    const float* wo_w      = (const float*)d_in[9];
    const float* qk_bos    = (const float*)d_in[10];
    const float* qk_prev   = (const float*)d_in[11];
    const float* qk_dir    = (const float*)d_in[12];
    const float* w1        = (const float*)d_in[13];
    const float* w2        = (const float*)d_in[14];
    float* out = (float*)d_out;

    float* attn_row0 = (float*)d_ws;                 // 2048
    float* mlp_row0  = attn_row0 + BB * VV;          // 2048
    float* v_bos     = mlp_row0 + BB * VV;           // 256
    float* sum0      = v_bos + VV;                   // 8
    float* w0        = sum0 + 8;                     // 16384
    float* wprev     = w0 + BB * NN;                 // 16384
    float* wzz       = wprev + BB * NN;              // 16384
    float* chunkSum  = wzz + BB * NN;                // BB*CHK*VV = 131072
    short* Xb            = (short*)(chunkSum + BB * CHK * VV);
    __hip_bfloat16* w1b  = (__hip_bfloat16*)(Xb + (size_t)BB * NN * VV);
    __hip_bfloat16* w2b  = w1b + HH * VV;

    prep_cvt_kernel<<<BB + 1 + (2 * HH * VV / 4) / 256, 256, 0, stream>>>(
        h, ln_attn_g, ln_attn_b, ln_mlp_g, ln_mlp_b, qk_dir, wo_w, wv_bos,
        w1, w2, attn_row0, mlp_row0, v_bos, sum0, w1b, w2b);
    scan_qkw_cvt_kernel<<<BB * CHK, 256, 0, stream>>>(h, mlp_row0, wv, qk_bos, qk_prev,
                                                      sum0, Xb, w0, wprev, wzz, chunkSum);
    attn_kernel<<<BB * CHK, 128, 0, stream>>>(Xb, wv, v_bos, w0, wprev, wzz, chunkSum, out);
    mlp_tp<<<256, 1024, 0, stream>>>((const short*)Xb, (const short*)w1b,
                                     (const short*)w2b, out);
}

// Round 10
// 187.261 us; speedup vs baseline: 1.1027x; 1.1027x over previous
//
#include <hip/hip_runtime.h>
#include <hip/hip_bf16.h>

#define BB 8
#define NN 2048
#define VV 256
#define HH 1024
#define CHK 64
#define RPC 32
constexpr float EPS = 1e-5f;

typedef __attribute__((ext_vector_type(4))) float floatx4;
typedef __attribute__((ext_vector_type(8))) short short8;

__device__ __forceinline__ void load_lds16(const void* g, void* l) {
    __builtin_amdgcn_global_load_lds((const __attribute__((address_space(1))) void*)g,
                                     (__attribute__((address_space(3))) void*)l, 16, 0, 0);
}
__device__ __forceinline__ float bf16s_to_f(short s) {
    unsigned u = ((unsigned)(unsigned short)s) << 16;
    return __builtin_bit_cast(float, u);
}

// ---------------------------------------------------------------------------
// K1: merged prep (blocks 0..8) + weight bf16 convert (blocks 9..)
// ---------------------------------------------------------------------------
__global__ void prep_cvt_kernel(const float* __restrict__ h,
                                const float* __restrict__ g_attn, const float* __restrict__ b_attn,
                                const float* __restrict__ g_mlp,  const float* __restrict__ b_mlp,
                                const float* __restrict__ qk_dir,
                                const float* __restrict__ wo_w,  const float* __restrict__ wv_bos,
                                const float* __restrict__ w1, const float* __restrict__ w2,
                                float* __restrict__ attn_row0, float* __restrict__ mlp_row0,
                                float* __restrict__ v_bos, float* __restrict__ sum0,
                                __hip_bfloat16* __restrict__ w1b, __hip_bfloat16* __restrict__ w2b)
{
    int t = threadIdx.x;
    if (blockIdx.x > BB) {
        int i = ((blockIdx.x - BB - 1) * 256 + t) * 4;
        const float* src;
        __hip_bfloat16* dst;
        if (i < HH * VV) { src = w1 + i; dst = w1b + i; }
        else             { src = w2 + (i - HH * VV); dst = w2b + (i - HH * VV); }
        float4 x = *reinterpret_cast<const float4*>(src);
        dst[0] = __float2bfloat16(x.x);
        dst[1] = __float2bfloat16(x.y);
        dst[2] = __float2bfloat16(x.z);
        dst[3] = __float2bfloat16(x.w);
        return;
    }
    __shared__ float red[VV];
    if (blockIdx.x < BB) {
        int b = blockIdx.x;
        float x = h[(size_t)b * NN * VV + t];
        red[t] = x; __syncthreads();
        for (int s = 128; s > 0; s >>= 1) { if (t < s) red[t] += red[t + s]; __syncthreads(); }
        float m = red[0] * (1.0f / VV); __syncthreads();
        float xc = x - m;
        red[t] = xc * xc; __syncthreads();
        for (int s = 128; s > 0; s >>= 1) { if (t < s) red[t] += red[t + s]; __syncthreads(); }
        float var = red[0] * (1.0f / VV); __syncthreads();
        float inv = 1.0f / sqrtf(var + EPS);
        float an = xc * inv * g_attn[t] + b_attn[t];
        float mn = xc * inv * g_mlp[t] + b_mlp[t];
        attn_row0[b * VV + t] = an;
        mlp_row0[b * VV + t]  = mn;
        red[t] = an * qk_dir[t]; __syncthreads();
        for (int s = 128; s > 0; s >>= 1) { if (t < s) red[t] += red[t + s]; __syncthreads(); }
        if (t == 0) sum0[b] = red[0];
    } else {
        const float4* wp = reinterpret_cast<const float4*>(wo_w + (size_t)t * VV);
        const float4* vp = reinterpret_cast<const float4*>(wv_bos);
        float acc = 0.f;
        for (int j = 0; j < VV / 4; ++j) {
            float4 a = wp[j], b = vp[j];
            acc += a.x * b.x + a.y * b.y + a.z * b.z + a.w * b.w;
        }
        v_bos[t] = acc;
    }
}

// ---------------------------------------------------------------------------
// K2: fused pass over h: bf16 convert (BOS row swap), softmax weights, and
//     scan chunk partials (bf16-rounded for consistency with attn_kernel).
// ---------------------------------------------------------------------------
__global__ __launch_bounds__(256) void scan_qkw_cvt_kernel(
    const float* __restrict__ h, const float* __restrict__ mlp_row0,
    const float* __restrict__ wv,
    const float* __restrict__ qk_bos, const float* __restrict__ qk_prev,
    const float* __restrict__ sum0,
    short* __restrict__ Xb,
    float* __restrict__ w0, float* __restrict__ wprev, float* __restrict__ wz,
    float* __restrict__ chunkSum)
{
    __shared__ float lds[4][VV];
    int wave = threadIdx.x >> 6, lane = threadIdx.x & 63;
    int b = blockIdx.x / CHK, c = blockIdx.x % CHK;
    int r0 = c * RPC + wave * 8;
    float4 wv4 = reinterpret_cast<const float4*>(wv)[lane];
    float4 qb4 = reinterpret_cast<const float4*>(qk_bos)[lane];
    float4 qp4 = reinterpret_cast<const float4*>(qk_prev)[lane];
    float s0b = sum0[b];
    float4 vsum = {0.f, 0.f, 0.f, 0.f};
#pragma unroll
    for (int rr = 0; rr < 8; ++rr) {
        int r = r0 + rr;
        size_t base = ((size_t)b * NN + r) * VV;
        float4 x = *reinterpret_cast<const float4*>(h + base + lane * 4);
        float4 xs = x;
        if (r == 0) xs = *reinterpret_cast<const float4*>(mlp_row0 + b * VV + lane * 4);
        __hip_bfloat16 c0 = __float2bfloat16(xs.x), c1 = __float2bfloat16(xs.y),
                       c2 = __float2bfloat16(xs.z), c3 = __float2bfloat16(xs.w);
        short4 pk;
        pk.x = *reinterpret_cast<short*>(&c0);
        pk.y = *reinterpret_cast<short*>(&c1);
        pk.z = *reinterpret_cast<short*>(&c2);
        pk.w = *reinterpret_cast<short*>(&c3);
        *reinterpret_cast<short4*>(Xb + base + lane * 4) = pk;
        if (r != 0) {
            vsum.x += bf16s_to_f(pk.x) * wv4.x; vsum.y += bf16s_to_f(pk.y) * wv4.y;
            vsum.z += bf16s_to_f(pk.z) * wv4.z; vsum.w += bf16s_to_f(pk.w) * wv4.w;
        }
        float s1 = x.x * qb4.x + x.y * qb4.y + x.z * qb4.z + x.w * qb4.w;
        float s2 = x.x * qp4.x + x.y * qp4.y + x.z * qp4.z + x.w * qp4.w;
        for (int off = 32; off > 0; off >>= 1) {
            s1 += __shfl_down(s1, off);
            s2 += __shfl_down(s2, off);
        }
        if (lane == 0) {
            int gid = b * NN + r;
            float W0, WP, WZ;
            if (r == 0) { W0 = 1.f; WP = 0.f; WZ = 0.f; }
            else if (r == 1) {
                float a = s1 * s0b + s2;
                float m = fmaxf(a, 0.f);
                float ea = expf(a - m), ez = expf(-m);
                float Z = ea + ez;
                W0 = ea / Z; WZ = ez / Z; WP = WZ;
            } else {
                float a = s1 * s0b;
                float m = fmaxf(fmaxf(a, s2), 0.f);
                float ea = expf(a - m), ed = expf(s2 - m), ez = expf(-m);
                float Z = ea + ed + (float)(r - 1) * ez;
                W0 = ea / Z; WP = ed / Z; WZ = ez / Z;
            }
            w0[gid] = W0; wprev[gid] = WP; wz[gid] = WZ;
        }
    }
    reinterpret_cast<float4*>(lds[wave])[lane] = vsum;
    __syncthreads();
    int v = threadIdx.x;
    chunkSum[((size_t)b * CHK + c) * VV + v] = lds[0][v] + lds[1][v] + lds[2][v] + lds[3][v];
}

// ---------------------------------------------------------------------------
// K3: attention emit — r==0 hoisted out of the loop; unroll-4 so the L2 loads
//     batch (4 independent loads in flight instead of a 1-load dependent chain)
// ---------------------------------------------------------------------------
__global__ __launch_bounds__(128) void attn_kernel(
    const short* __restrict__ Xb, const float* __restrict__ wv,
    const float* __restrict__ v_bos,
    const float* __restrict__ w0, const float* __restrict__ wprev,
    const float* __restrict__ wz, const float* __restrict__ chunkSum,
    float* __restrict__ out)
{
    int b = blockIdx.x / CHK, c = blockIdx.x % CHK;
    int v = threadIdx.x * 2;
    float2 wv2 = *reinterpret_cast<const float2*>(wv + v);
    float2 vb2 = *reinterpret_cast<const float2*>(v_bos + v);
    float2 S = {0.f, 0.f};
    for (int cc = 0; cc < c; ++cc) {
        float2 t = *reinterpret_cast<const float2*>(chunkSum + (b * CHK + cc) * VV + v);
        S.x += t.x; S.y += t.y;
    }
    int r0 = c * RPC;
    int rstart = r0;
    float2 prev = {0.f, 0.f};
    if (c == 0) {
        *reinterpret_cast<float2*>(out + (size_t)b * NN * VV + v) = vb2;
        rstart = 1;
    } else {
        short2 p = *reinterpret_cast<const short2*>(Xb + ((size_t)b * NN + r0 - 1) * VV + v);
        prev.x = bf16s_to_f(p.x) * wv2.x; prev.y = bf16s_to_f(p.y) * wv2.y;
    }
    int rend = r0 + RPC;
#pragma unroll 4
    for (int r = rstart; r < rend; ++r) {
        size_t idx = ((size_t)b * NN + r) * VV + v;
        short2 xv = *reinterpret_cast<const short2*>(Xb + idx);
        float2 val;
        val.x = bf16s_to_f(xv.x) * wv2.x; val.y = bf16s_to_f(xv.y) * wv2.y;
        S.x += val.x; S.y += val.y;
        int wi = b * NN + r;
        float W0 = w0[wi], WD = wprev[wi] - wz[wi], WZ = wz[wi];
        float2 o;
        o.x = W0 * vb2.x + WD * prev.x + WZ * S.x;
        o.y = W0 * vb2.y + WD * prev.y + WZ * S.y;
        prev = val;
        *reinterpret_cast<float2*>(out + idx) = o;
    }
}

// ---------------------------------------------------------------------------
// K4: fused MLP v5  out += relu(X @ w1^T) @ w2^T
//   R6's exact compute layout (8 waves wm2 x wn4, M-tile 64, H-chunk 64,
//   A-from-regs GEMM1 32x16, GEMM2 32x64, XOR seg-swizzle) but SINGLE-buffered
//   weights: LDS = 32+32+8 = 72 KB -> 2 blocks/CU. Intra-block prefetch is
//   gone (3 barriers/hc); the co-resident block's compute covers the DMA
//   drain and barrier stalls instead.
// ---------------------------------------------------------------------------
__global__ __launch_bounds__(512) void mlp_fused5(const short* __restrict__ Xb,
                                                  const short* __restrict__ w1b,
                                                  const short* __restrict__ w2b,
                                                  float* __restrict__ out)
{
    __shared__ __align__(16) short sW1[64 * 256];  // 32 KB [h-row][k]
    __shared__ __align__(16) short sW2[256 * 64];  // 32 KB [v-row][h-k]
    __shared__ __align__(16) short sY[64 * 64];    // 8 KB  [row][h-col]
    int wave = threadIdx.x >> 6, lane = threadIdx.x & 63;
    int wm = wave >> 2, wn = wave & 3;
    int ra = lane & 15, q = lane >> 4;
    int m0 = blockIdx.x * 64;

    // X fragments: this wave's wm-half (32 rows), full K=256
    short8 xf[8][2];
#pragma unroll
    for (int ks = 0; ks < 8; ++ks)
#pragma unroll
        for (int i = 0; i < 2; ++i)
            xf[ks][i] = *reinterpret_cast<const short8*>(
                Xb + (size_t)(m0 + wm * 32 + i * 16 + ra) * VV + ks * 32 + q * 8);

    floatx4 oacc[2][4];
#pragma unroll
    for (int i = 0; i < 2; ++i)
#pragma unroll
        for (int j = 0; j < 4; ++j) oacc[i][j] = floatx4{0.f, 0.f, 0.f, 0.f};

    for (int hc = 0; hc < 16; ++hc) {
        __syncthreads();   // prev iter's reads of sW1/sW2 complete
        // ---- stage weights (single buffer) ----
#pragma unroll
        for (int it = 0; it < 4; ++it) {
            int g = wave * 4 + it;
            int n = g * 2 + (lane >> 5);
            int slot = lane & 31;
            load_lds16(w1b + (size_t)(hc * 64 + n) * VV + ((slot ^ (n & 7)) * 8),
                       sW1 + g * 512);
        }
#pragma unroll
        for (int it = 0; it < 4; ++it) {
            int g = wave * 4 + it;
            int v = g * 8 + (lane >> 3);
            int slot = lane & 7;
            load_lds16(w2b + (size_t)v * HH + hc * 64 + ((slot ^ (v & 7)) * 8),
                       sW2 + g * 512);
        }
        __syncthreads();   // staged + visible

        // ---- GEMM1: Y[wm*32..+32][wn*16..+16] = X @ w1c^T (A from regs) ----
        floatx4 yacc[2];
        yacc[0] = floatx4{0.f, 0.f, 0.f, 0.f};
        yacc[1] = floatx4{0.f, 0.f, 0.f, 0.f};
        int nb = wn * 16 + ra;
#pragma unroll
        for (int ks = 0; ks < 8; ++ks) {
            short8 bfr = *reinterpret_cast<const short8*>(
                &sW1[nb * 256 + (((ks * 4 + q) ^ (ra & 7)) * 8)]);
#pragma unroll
            for (int i = 0; i < 2; ++i)
                yacc[i] = __builtin_amdgcn_mfma_f32_16x16x32_bf16(xf[ks][i], bfr, yacc[i], 0, 0, 0);
        }
        // relu -> bf16 -> sY (swizzled)
#pragma unroll
        for (int i = 0; i < 2; ++i)
#pragma unroll
            for (int reg = 0; reg < 4; ++reg) {
                int m = wm * 32 + i * 16 + q * 4 + reg;
                int ke = wn * 16 + ra;
                __hip_bfloat16 hb = __float2bfloat16(fmaxf(yacc[i][reg], 0.f));
                sY[m * 64 + (((ke >> 3) ^ (m & 7)) * 8) + (ke & 7)] =
                    *reinterpret_cast<short*>(&hb);
            }
        __syncthreads();   // sY visible

        // ---- GEMM2: oacc[wm*32..+32][wn*64..+64] += Yc @ w2c^T ----
#pragma unroll
        for (int kk = 0; kk < 2; ++kk) {
            short8 a2[2];
#pragma unroll
            for (int i = 0; i < 2; ++i) {
                int m = wm * 32 + i * 16 + ra;
                a2[i] = *reinterpret_cast<const short8*>(
                    &sY[m * 64 + (((kk * 4 + q) ^ (ra & 7)) * 8)]);
            }
#pragma unroll
            for (int j = 0; j < 4; ++j) {
                int v = wn * 64 + j * 16 + ra;
                short8 b2 = *reinterpret_cast<const short8*>(
                    &sW2[v * 64 + (((kk * 4 + q) ^ (ra & 7)) * 8)]);
#pragma unroll
                for (int i = 0; i < 2; ++i)
                    oacc[i][j] = __builtin_amdgcn_mfma_f32_16x16x32_bf16(a2[i], b2, oacc[i][j], 0, 0, 0);
            }
        }
    }

    // ---- epilogue: out += oacc (attn wrote out first) ----
#pragma unroll
    for (int i = 0; i < 2; ++i)
#pragma unroll
        for (int j = 0; j < 4; ++j)
#pragma unroll
            for (int reg = 0; reg < 4; ++reg) {
                int row = m0 + wm * 32 + i * 16 + q * 4 + reg;
                int col = wn * 64 + j * 16 + ra;
                out[(size_t)row * VV + col] += oacc[i][j][reg];
            }
}

// ---------------------------------------------------------------------------
extern "C" void kernel_launch(void* const* d_in, const int* in_sizes, int n_in,
                              void* d_out, int out_size, void* d_ws, size_t ws_size,
                              hipStream_t stream)
{
    const float* h        = (const float*)d_in[0];
    const float* ln_attn_g = (const float*)d_in[3];
    const float* ln_attn_b = (const float*)d_in[4];
    const float* ln_mlp_g  = (const float*)d_in[5];
    const float* ln_mlp_b  = (const float*)d_in[6];
    const float* wv        = (const float*)d_in[7];
    const float* wv_bos    = (const float*)d_in[8];
    const float* wo_w      = (const float*)d_in[9];
    const float* qk_bos    = (const float*)d_in[10];
    const float* qk_prev   = (const float*)d_in[11];
    const float* qk_dir    = (const float*)d_in[12];
    const float* w1        = (const float*)d_in[13];
    const float* w2        = (const float*)d_in[14];
    float* out = (float*)d_out;

    float* attn_row0 = (float*)d_ws;                 // 2048
    float* mlp_row0  = attn_row0 + BB * VV;          // 2048
    float* v_bos     = mlp_row0 + BB * VV;           // 256
    float* sum0      = v_bos + VV;                   // 8
    float* w0        = sum0 + 8;                     // 16384
    float* wprev     = w0 + BB * NN;                 // 16384
    float* wzz       = wprev + BB * NN;              // 16384
    float* chunkSum  = wzz + BB * NN;                // BB*CHK*VV = 131072
    short* Xb            = (short*)(chunkSum + BB * CHK * VV);
    __hip_bfloat16* w1b  = (__hip_bfloat16*)(Xb + (size_t)BB * NN * VV);
    __hip_bfloat16* w2b  = w1b + HH * VV;

    prep_cvt_kernel<<<BB + 1 + (2 * HH * VV / 4) / 256, 256, 0, stream>>>(
        h, ln_attn_g, ln_attn_b, ln_mlp_g, ln_mlp_b, qk_dir, wo_w, wv_bos,
        w1, w2, attn_row0, mlp_row0, v_bos, sum0, w1b, w2b);
    scan_qkw_cvt_kernel<<<BB * CHK, 256, 0, stream>>>(h, mlp_row0, wv, qk_bos, qk_prev,
                                                      sum0, Xb, w0, wprev, wzz, chunkSum);
    attn_kernel<<<BB * CHK, 128, 0, stream>>>(Xb, wv, v_bos, w0, wprev, wzz, chunkSum, out);
    mlp_fused5<<<256, 512, 0, stream>>>((const short*)Xb, (const short*)w1b,
                                        (const short*)w2b, out);
}